// Round 4
// baseline (287.424 us; speedup 1.0000x reference)
//
#include <hip/hip_runtime.h>

// EdgeMLP: f = (relu(x@W1+b1)@W2+b2) for both edge sets, then masked pairwise
// cosine similarity out[i][j] = (cls1[i]==cls2[j]) * dot(f1_hat[i], f2_hat[j]).
// Stage 1: normalized bf16 features + int labels into ws.
// Stage 2: per wave, one 32x256 output region via 8x mfma_f32_32x32x16_bf16
//   tile-pairs, masked into a PRIVATE 32KiB LDS buffer (no __syncthreads),
//   then streamed out as 32 dwordx4 stores, each one fully contiguous 1KiB
//   row chunk (8 full 128B lines) -- fill-kernel-style sequential writes.

typedef __bf16 bf16x8 __attribute__((ext_vector_type(8)));
typedef float floatx16 __attribute__((ext_vector_type(16)));

__global__ __launch_bounds__(256) void mlp_norm_kernel(
    const float* __restrict__ e1, const float* __restrict__ e2,
    const float* __restrict__ W1, const float* __restrict__ b1,
    const float* __restrict__ W2, const float* __restrict__ b2,
    __bf16* __restrict__ f1b, __bf16* __restrict__ f2b,
    int* __restrict__ cls1, int* __restrict__ cls2, int N1, int N2)
{
    __shared__ float sW1[192];
    __shared__ float sb1[64];
    __shared__ float sW2[2048];
    __shared__ float sb2[32];
    for (int i = threadIdx.x; i < 192; i += 256) sW1[i] = W1[i];
    if (threadIdx.x < 64) sb1[threadIdx.x] = b1[threadIdx.x];
    for (int i = threadIdx.x; i < 2048; i += 256) sW2[i] = W2[i];
    if (threadIdx.x < 32) sb2[threadIdx.x] = b2[threadIdx.x];
    __syncthreads();

    int t = blockIdx.x * 256 + threadIdx.x;
    if (t >= N1 + N2) return;

    const float* src;
    __bf16* fout;
    int* cout;
    int row;
    if (t < N1) { row = t;      src = e1 + (size_t)row * 4; fout = f1b; cout = cls1; }
    else        { row = t - N1; src = e2 + (size_t)row * 4; fout = f2b; cout = cls2; }

    float x0 = src[0], x1 = src[1], x2 = src[2];
    int lbl = (int)src[3];

    float f[32];
#pragma unroll
    for (int k = 0; k < 32; ++k) f[k] = sb2[k];

    for (int j = 0; j < 64; ++j) {
        float h = fmaf(x0, sW1[j], fmaf(x1, sW1[64 + j], fmaf(x2, sW1[128 + j], sb1[j])));
        h = fmaxf(h, 0.0f);
#pragma unroll
        for (int k = 0; k < 32; ++k) f[k] = fmaf(h, sW2[j * 32 + k], f[k]);
    }

    float ss = 0.0f;
#pragma unroll
    for (int k = 0; k < 32; ++k) ss = fmaf(f[k], f[k], ss);
    float n = sqrtf(ss);
    float scale = (n > 1e-20f) ? (1.0f / n) : 0.0f;

    __bf16* dst = fout + (size_t)row * 32;
#pragma unroll
    for (int k = 0; k < 32; ++k) dst[k] = (__bf16)(f[k] * scale);
    cout[row] = lbl;
}

// One wave per block (64 threads), 32KiB private LDS staging buffer.
// A/B frag layout (32x32x16): row(A)/col(B)=lane&31, k=(lane>>5)*8 + j.
// C/D layout: col=lane&31, row=(reg&3)+8*(reg>>2)+4*(lane>>5).
__global__ __launch_bounds__(64) void pair_cos_kernel(
    const __bf16* __restrict__ f1b, const __bf16* __restrict__ f2b,
    const int* __restrict__ cls1, const int* __restrict__ cls2,
    float* __restrict__ out, int N2, int ncg)
{
    __shared__ float wbuf[32 * 256];  // 32 KiB, wave-private (1 wave/block)
    const int lane = threadIdx.x & 63;
    const int wid = blockIdx.x;
    const int istrip = wid / ncg;
    const int cg = wid - istrip * ncg;
    const int i0 = istrip * 32;
    const int j0 = cg * 256;
    const int l31 = lane & 31;
    const int hi = lane >> 5;

    const __bf16* arow = f1b + (size_t)(i0 + l31) * 32 + hi * 8;
    bf16x8 a0 = *(const bf16x8*)(arow);
    bf16x8 a1 = *(const bf16x8*)(arow + 16);

    int c1r[16];
#pragma unroll
    for (int g = 0; g < 4; ++g) {
        int4 v = *(const int4*)(cls1 + i0 + 8 * g + 4 * hi);
        c1r[g * 4 + 0] = v.x; c1r[g * 4 + 1] = v.y;
        c1r[g * 4 + 2] = v.z; c1r[g * 4 + 3] = v.w;
    }

#pragma unroll
    for (int t = 0; t < 8; ++t) {
        int j = j0 + t * 32;
        const __bf16* brow = f2b + (size_t)(j + l31) * 32 + hi * 8;
        bf16x8 b0 = *(const bf16x8*)(brow);
        bf16x8 b1 = *(const bf16x8*)(brow + 16);
        int c2v = cls2[j + l31];

        floatx16 acc = {};
        acc = __builtin_amdgcn_mfma_f32_32x32x16_bf16(a0, b0, acc, 0, 0, 0);
        acc = __builtin_amdgcn_mfma_f32_32x32x16_bf16(a1, b1, acc, 0, 0, 0);

        // masked scatter into LDS: addr = row*256 + t*32 + l31
        // lanes 0..31 hit distinct banks; lanes 32..63 alias 2-way (free).
#pragma unroll
        for (int g = 0; g < 4; ++g) {
#pragma unroll
            for (int m = 0; m < 4; ++m) {
                int reg = g * 4 + m;
                int row = m + 8 * g + 4 * hi;
                float v = (c1r[reg] == c2v) ? acc[reg] : 0.0f;
                wbuf[row * 256 + t * 32 + l31] = v;
            }
        }
    }
    asm volatile("s_waitcnt lgkmcnt(0)" ::: "memory");

    // stream out: one dwordx4 per row = 1KiB fully contiguous (8 full lines).
#pragma unroll 4
    for (int r = 0; r < 32; ++r) {
        float4 v = *(const float4*)(wbuf + r * 256 + lane * 4);
        float* dst = out + (size_t)(i0 + r) * N2 + j0 + lane * 4;
        *(float4*)dst = v;
    }
}

extern "C" void kernel_launch(void* const* d_in, const int* in_sizes, int n_in,
                              void* d_out, int out_size, void* d_ws, size_t ws_size,
                              hipStream_t stream) {
    const float* e1 = (const float*)d_in[0];
    const float* e2 = (const float*)d_in[1];
    const float* W1 = (const float*)d_in[2];
    const float* b1 = (const float*)d_in[3];
    const float* W2 = (const float*)d_in[4];
    const float* b2 = (const float*)d_in[5];
    float* out = (float*)d_out;

    const int N1 = in_sizes[0] / 4;  // 8192
    const int N2 = in_sizes[1] / 4;  // 8192

    char* ws = (char*)d_ws;
    __bf16* f1b = (__bf16*)ws;                                   // N1*32 bf16
    __bf16* f2b = (__bf16*)(ws + (size_t)N1 * 64);               // N2*32 bf16
    int* cls1 = (int*)(ws + (size_t)(N1 + N2) * 64);             // N1 ints
    int* cls2 = cls1 + N1;                                       // N2 ints

    int nrows = N1 + N2;
    mlp_norm_kernel<<<(nrows + 255) / 256, 256, 0, stream>>>(
        e1, e2, W1, b1, W2, b2, f1b, f2b, cls1, cls2, N1, N2);

    int ncg = N2 / 256;                 // 32 col-groups of 256
    int nwaves = (N1 / 32) * ncg;       // 8192 waves, 1 per block
    pair_cos_kernel<<<nwaves, 64, 0, stream>>>(
        f1b, f2b, cls1, cls2, out, N2, ncg);
}